// Round 1
// 530.330 us; speedup vs baseline: 1.1289x; 1.1289x over previous
//
#include <hip/hip_runtime.h>
#include <hip/hip_bf16.h>
#include <math.h>

typedef __attribute__((ext_vector_type(8))) short short8;   // 8 x bf16 (4 VGPRs)
typedef __attribute__((ext_vector_type(4))) float f32x4;    // MFMA C/D frag

#define NN    21
#define DD    256
#define GH    512
#define NE    40
#define BT    3               // batches per workgroup
#define MROWS (BT * NN)       // 63 real rows
#define MPAD  64              // padded M tile
#define NTHR  256
#define UVSTR 36              // fp32 row stride for uv (32 + 4)

__device__ __forceinline__ f32x4 mfma16(short8 a, short8 b, f32x4 c) {
    return __builtin_amdgcn_mfma_f32_16x16x32_bf16(a, b, c, 0, 0, 0);
}

// ---------------------------------------------------------------------------
// Prep: transpose weights to bf16 [n][k] layouts. WvT[f][d] = Wv[d][f];
// WtT[h][c] = W1[c][h] (c<256); WbT[h][c] = W1[256+c][h].
// ---------------------------------------------------------------------------
__global__ void prep_weights(const float* __restrict__ Wv, const float* __restrict__ W1,
                             __hip_bfloat16* __restrict__ WvT,
                             __hip_bfloat16* __restrict__ WtT,
                             __hip_bfloat16* __restrict__ WbT) {
    __shared__ float tile[64][65];
    int bi = blockIdx.x;
    const float* src;
    int ld, tc, th;
    bool isW1 = bi < 64;
    if (isW1) { src = W1; ld = 512; tc = (bi & 7) * 64; th = (bi >> 3) * 64; }
    else      { int b = bi - 64; src = Wv; ld = 256; tc = (b & 3) * 64; th = (b >> 2) * 64; }
    for (int i = 0; i < 16; ++i) {
        int e = threadIdx.x + 256 * i;
        int r = e >> 6, cc = e & 63;
        tile[r][cc] = src[(size_t)(tc + r) * ld + th + cc];
    }
    __syncthreads();
    for (int i = 0; i < 16; ++i) {
        int e  = threadIdx.x + 256 * i;
        int r2 = e >> 6, cc2 = e & 63;
        float v = tile[cc2][r2];
        int hh = th + r2, c = tc + cc2;
        if (isW1) {
            if (c < 256) WtT[hh * 256 + c]         = __float2bfloat16(v);
            else         WbT[hh * 256 + (c - 256)] = __float2bfloat16(v);
        } else {
            WvT[hh * 256 + c] = __float2bfloat16(v);
        }
    }
}

// one gelu*sigmoid*w2 partial term
#define GELU_GATE(zu, zv, zb, zw)  do {                              \
    float z_ = (zu) + (zv) + (zb);                                   \
    float y_ = 1.5957691216f * (z_ + 0.044715f * z_ * z_ * z_);      \
    float s_ = 1.0f / (1.0f + __expf(-y_));                          \
    gacc += z_ * s_ * (zw); } while (0)

// ---------------------------------------------------------------------------
// Fused kernel. 1 WG = 3 batches (63 rows, pad 64), 256 threads / 4 waves.
// A-fragments live in registers; xs LDS region is reused as wst+uv.
// XOR swizzle: content 16B-granule g of row r stored at phys granule g^(r&7).
// T14: next chunk's weight tile is loaded to registers BEFORE the MFMA phase
// (latency hides under MFMA+uv-writes), ds_written after the first barrier.
// ---------------------------------------------------------------------------
__launch_bounds__(NTHR, 4)
__global__ void fused_kernel(const float* __restrict__ hin,
                             const int* __restrict__ srci, const int* __restrict__ dsti,
                             const float* __restrict__ lnw, const float* __restrict__ lnb,
                             const float* __restrict__ bv,  const float* __restrict__ b1,
                             const float* __restrict__ W2,  const float* __restrict__ b2,
                             const __hip_bfloat16* __restrict__ WvT,
                             const __hip_bfloat16* __restrict__ WtT,
                             const __hip_bfloat16* __restrict__ WbT,
                             float* __restrict__ out, int Btotal) {
    // phase A: xs[64 rows][512 B] swizzled bf16 (32 KB)
    // phase B: wst = smem[0..16384) (32 rows x 512 B swizzled bf16),
    //          uv  = (float*)(smem+16384), [64][UVSTR] (9.2 KB)
    __shared__ __align__(16) char smem[32768];
    __shared__ __align__(16) float b1s[GH], w2s[GH], bvs[DD];
    __shared__ float gates[BT * NE];
    __shared__ int   srcs[NE], dsts[NE];
    __shared__ int   csr_off[NN + 1], csr_cur[NN], csr_eid[NE];

    const int tid  = threadIdx.x;
    const int lane = tid & 63;
    const int w    = tid >> 6;          // wave 0..3
    const int b0   = blockIdx.x * BT;

    if (tid < NE) { srcs[tid] = srci[tid]; dsts[tid] = dsti[tid]; }
    b1s[tid] = b1[tid];  b1s[tid + 256] = b1[tid + 256];
    w2s[tid] = W2[tid];  w2s[tid + 256] = W2[tid + 256];
    bvs[tid] = bv[tid];
    if (tid <= NN) csr_off[tid] = 0;
    int myd = (tid < NE) ? dsti[tid] : 0;
    __syncthreads();
    if (tid < NE) atomicAdd(&csr_off[myd + 1], 1);

    // ---- staging geometry (chunk-invariant): thread covers rows s_row0+8i ----
    const int s_row0 = tid >> 5;              // 0..7
    const int s_pg   = tid & 31;              // phys 16B granule in row
    const int s_cg   = s_pg ^ (s_row0 & 7);   // content granule (row&7 == s_row0&7)
    char* const s_dst = smem + s_row0 * 512 + s_pg * 16;          // + i*4096
    const __hip_bfloat16* const s_wt = WtT + (size_t)s_row0 * 256 + s_cg * 8;
    const __hip_bfloat16* const s_wb = WbT + (size_t)s_row0 * 256 + s_cg * 8;
    const __hip_bfloat16* const s_wv = WvT + (size_t)s_row0 * 256 + s_cg * 8;

    // ---- Phase 1: LayerNorm -> xs (bf16, swizzled) ----
    {
        float4 wgt = ((const float4*)lnw)[lane];
        float4 bta = ((const float4*)lnb)[lane];
        for (int r = w; r < MPAD; r += 4) {
            int b_loc = r / NN;
            int node  = r - b_loc * NN;
            bool valid = (r < MROWS) && (b0 + b_loc < Btotal);
            float4 h4 = {0.f, 0.f, 0.f, 0.f};
            if (valid)
                h4 = *(const float4*)(hin + ((size_t)(b0 + b_loc) * NN + node) * DD + lane * 4);
            float s  = h4.x + h4.y + h4.z + h4.w;
            float ss = h4.x*h4.x + h4.y*h4.y + h4.z*h4.z + h4.w*h4.w;
            for (int off = 32; off; off >>= 1) {
                s  += __shfl_xor(s,  off);
                ss += __shfl_xor(ss, off);
            }
            float mu   = s * (1.0f / 256.0f);
            float rstd = rsqrtf(ss * (1.0f / 256.0f) - mu * mu + 1e-5f);
            __align__(8) __hip_bfloat16 t[4];
            if (valid) {
                t[0] = __float2bfloat16((h4.x - mu) * rstd * wgt.x + bta.x);
                t[1] = __float2bfloat16((h4.y - mu) * rstd * wgt.y + bta.y);
                t[2] = __float2bfloat16((h4.z - mu) * rstd * wgt.z + bta.z);
                t[3] = __float2bfloat16((h4.w - mu) * rstd * wgt.w + bta.w);
            } else {
                __hip_bfloat16 z = __float2bfloat16(0.0f);
                t[0] = z; t[1] = z; t[2] = z; t[3] = z;
            }
            char* dst = smem + r * 512 + ((((lane >> 1) ^ (r & 7)) << 4) | ((lane & 1) << 3));
            *(ushort4*)dst = *(ushort4*)&t[0];
        }
    }
    __syncthreads();

    // ---- CSR build (thread 0, overlapped with A-frag loads) ----
    if (tid == 0) {
        for (int n = 0; n < NN; ++n) csr_off[n + 1] += csr_off[n];
        for (int n = 0; n < NN; ++n) csr_cur[n] = csr_off[n];
        for (int e = 0; e < NE; ++e) { int d = dsts[e]; csr_eid[csr_cur[d]++] = e; }
    }

    // ---- A-fragments -> registers (wave grid: mq = m-half, nsel = U/V) ----
    const int mq   = w & 1;
    const int nsel = w >> 1;
    const int l15  = lane & 15;
    const int lq   = lane >> 4;
    short8 afr[2][8];
    #pragma unroll
    for (int mt = 0; mt < 2; ++mt) {
        int r = 32 * mq + 16 * mt + l15;
        const char* rowp = smem + r * 512;
        int swz = r & 7;
        #pragma unroll
        for (int ki = 0; ki < 8; ++ki)
            afr[mt][ki] = *(const short8*)(rowp + ((((ki << 2) + lq) ^ swz) << 4));
    }
    __syncthreads();   // xs dead beyond this point; smem becomes wst, +16K uv

    float* uvp = (float*)(smem + 16384);

    // gate ownership: pair p = tid>>1 (120 pairs), j-half = tid&1
    const bool gactive = tid < 2 * BT * NE;   // 240
    int rs = 0, rd = 0;
    if (gactive) {
        int p  = tid >> 1;
        int pb = p / NE, pe = p - pb * NE;
        rs = pb * NN + srcs[pe];
        rd = pb * NN + dsts[pe];
    }
    const int jh = tid & 1;

    // stage U/V chunk 0: wst rows 0-15 <- WtT rows 0..15, rows 16-31 <- WbT
    {
        *(float4*)(s_dst         ) = *(const float4*)(s_wt       );
        *(float4*)(s_dst +  4096 ) = *(const float4*)(s_wt + 2048);
        *(float4*)(s_dst +  8192 ) = *(const float4*)(s_wb       );
        *(float4*)(s_dst + 12288 ) = *(const float4*)(s_wb + 2048);
    }
    __syncthreads();

    // ---- Phase 2: 32 chunks of 16 gh-cols (U and V simultaneously) ----
    float gacc = 0.0f;
    const int   brow_r = 16 * nsel + l15;
    const char* browp  = smem + brow_r * 512;
    const int   bswz   = l15 & 7;
    for (int c = 0; c < 32; ++c) {
        // T14: issue next chunk's weight loads FIRST (hide under MFMA)
        float4 stg0, stg1, stg2, stg3;
        if (c + 1 < 32) {
            const __hip_bfloat16* pt = s_wt + (size_t)(c + 1) * 4096;
            const __hip_bfloat16* pb = s_wb + (size_t)(c + 1) * 4096;
            stg0 = *(const float4*)(pt       );
            stg1 = *(const float4*)(pt + 2048);
            stg2 = *(const float4*)(pb       );
            stg3 = *(const float4*)(pb + 2048);
        }
        f32x4 acc0 = {0.f,0.f,0.f,0.f}, acc1 = {0.f,0.f,0.f,0.f};
        #pragma unroll
        for (int ki = 0; ki < 8; ++ki) {
            short8 bf = *(const short8*)(browp + ((((ki << 2) + lq) ^ bswz) << 4));
            acc0 = mfma16(afr[0][ki], bf, acc0);
            acc1 = mfma16(afr[1][ki], bf, acc1);
        }
        #pragma unroll
        for (int r = 0; r < 4; ++r) {
            int col = 16 * nsel + l15;
            uvp[(32 * mq +      4 * lq + r) * UVSTR + col] = acc0[r];
            uvp[(32 * mq + 16 + 4 * lq + r) * UVSTR + col] = acc1[r];
        }
        __syncthreads();
        // staging writes from registers (fire-and-forget, drains at barrier)
        if (c + 1 < 32) {
            *(float4*)(s_dst        ) = stg0;
            *(float4*)(s_dst +  4096) = stg1;
            *(float4*)(s_dst +  8192) = stg2;
            *(float4*)(s_dst + 12288) = stg3;
        }
        // gate partials (vectorized float4 reads of uv/b1/w2)
        if (gactive) {
            const float4* up4 = (const float4*)(uvp + rs * UVSTR + jh * 8);
            const float4* vp4 = (const float4*)(uvp + rd * UVSTR + 16 + jh * 8);
            const float4* b14 = (const float4*)(b1s + c * 16 + jh * 8);
            const float4* w24 = (const float4*)(w2s + c * 16 + jh * 8);
            float4 ua = up4[0], ub = up4[1];
            float4 va = vp4[0], vb = vp4[1];
            float4 ba = b14[0], bb = b14[1];
            float4 wa = w24[0], wb = w24[1];
            GELU_GATE(ua.x, va.x, ba.x, wa.x);
            GELU_GATE(ua.y, va.y, ba.y, wa.y);
            GELU_GATE(ua.z, va.z, ba.z, wa.z);
            GELU_GATE(ua.w, va.w, ba.w, wa.w);
            GELU_GATE(ub.x, vb.x, bb.x, wb.x);
            GELU_GATE(ub.y, vb.y, bb.y, wb.y);
            GELU_GATE(ub.z, vb.z, bb.z, wb.z);
            GELU_GATE(ub.w, vb.w, bb.w, wb.w);
        }
        __syncthreads();
    }

    // ---- Phase 3: finalize gates (shuffle-pair reduce) + stage Val chunk 0 ----
    if (gactive) {
        float other = __shfl_xor(gacc, 1);
        if (jh == 0) {
            float tot = gacc + other + b2[0];
            gates[tid >> 1] = 1.0f / (1.0f + __expf(-tot));
        }
    }
    {
        *(float4*)(s_dst        ) = *(const float4*)(s_wv       );
        *(float4*)(s_dst +  4096) = *(const float4*)(s_wv + 2048);
        *(float4*)(s_dst +  8192) = *(const float4*)(s_wv + 4096);
        *(float4*)(s_dst + 12288) = *(const float4*)(s_wv + 6144);
    }
    __syncthreads();

    // ---- Phase 4: 8 Val chunks (32 f-cols) -> CSR aggregation -> out ----
    for (int vc = 0; vc < 8; ++vc) {
        // T14: issue next chunk's WvT loads first
        float4 stg0, stg1, stg2, stg3;
        if (vc + 1 < 8) {
            const __hip_bfloat16* pv = s_wv + (size_t)(vc + 1) * 8192;
            stg0 = *(const float4*)(pv       );
            stg1 = *(const float4*)(pv + 2048);
            stg2 = *(const float4*)(pv + 4096);
            stg3 = *(const float4*)(pv + 6144);
        }
        f32x4 acc0 = {0.f,0.f,0.f,0.f}, acc1 = {0.f,0.f,0.f,0.f};
        #pragma unroll
        for (int ki = 0; ki < 8; ++ki) {
            short8 bf = *(const short8*)(browp + ((((ki << 2) + lq) ^ bswz) << 4));
            acc0 = mfma16(afr[0][ki], bf, acc0);
            acc1 = mfma16(afr[1][ki], bf, acc1);
        }
        #pragma unroll
        for (int r = 0; r < 4; ++r) {
            int col = 16 * nsel + l15;
            float bvv = bvs[vc * 32 + col];
            uvp[(32 * mq +      4 * lq + r) * UVSTR + col] = acc0[r] + bvv;
            uvp[(32 * mq + 16 + 4 * lq + r) * UVSTR + col] = acc1[r] + bvv;
        }
        __syncthreads();
        if (vc + 1 < 8) {
            *(float4*)(s_dst        ) = stg0;
            *(float4*)(s_dst +  4096) = stg1;
            *(float4*)(s_dst +  8192) = stg2;
            *(float4*)(s_dst + 12288) = stg3;
        }
        // aggregation (reads uv/gates/csr) overlapped with staging writes
        for (int q = tid; q < MROWS * 8; q += NTHR) {
            int row = q >> 3, g = q & 7;
            int b_loc = row / NN;
            int node  = row - b_loc * NN;
            if (b0 + b_loc < Btotal) {
                size_t ga = ((size_t)(b0 + b_loc) * NN + node) * DD + vc * 32 + g * 4;
                float4 hv = *(const float4*)(hin + ga);
                float a0 = hv.x, a1 = hv.y, a2 = hv.z, a3 = hv.w;
                int e1 = csr_off[node + 1];
                for (int ii = csr_off[node]; ii < e1; ++ii) {
                    int e  = csr_eid[ii];
                    float gv = gates[b_loc * NE + e];
                    const float* vp = uvp + (b_loc * NN + srcs[e]) * UVSTR + g * 4;
                    a0 += gv * vp[0]; a1 += gv * vp[1];
                    a2 += gv * vp[2]; a3 += gv * vp[3];
                }
                float4 o = {a0, a1, a2, a3};
                *(float4*)(out + ga) = o;
            }
        }
        __syncthreads();
    }
}

extern "C" void kernel_launch(void* const* d_in, const int* in_sizes, int n_in,
                              void* d_out, int out_size, void* d_ws, size_t ws_size,
                              hipStream_t stream) {
    const float* h   = (const float*)d_in[0];
    const int*  srci = (const int*)d_in[1];
    const int*  dsti = (const int*)d_in[2];
    const float* lnw = (const float*)d_in[3];
    const float* lnb = (const float*)d_in[4];
    const float* Wv  = (const float*)d_in[5];
    const float* bv  = (const float*)d_in[6];
    const float* W1  = (const float*)d_in[7];
    const float* b1  = (const float*)d_in[8];
    const float* W2  = (const float*)d_in[9];
    const float* b2  = (const float*)d_in[10];
    float* out = (float*)d_out;

    __hip_bfloat16* WvT = (__hip_bfloat16*)d_ws;       // 256*256
    __hip_bfloat16* WtT = WvT + 256 * 256;             // 512*256
    __hip_bfloat16* WbT = WtT + 512 * 256;             // 512*256

    int Btotal = in_sizes[0] / (NN * DD);
    prep_weights<<<80, 256, 0, stream>>>(Wv, W1, WvT, WtT, WbT);
    int grid = (Btotal + BT - 1) / BT;
    fused_kernel<<<grid, NTHR, 0, stream>>>(h, srci, dsti, lnw, lnb, bv, b1, W2, b2,
                                            WvT, WtT, WbT, out, Btotal);
}